// Round 4
// baseline (643.033 us; speedup 1.0000x reference)
//
#include <hip/hip_runtime.h>

typedef __bf16 bf16;
typedef __bf16 bf16x8 __attribute__((ext_vector_type(8)));
typedef float floatx4 __attribute__((ext_vector_type(4)));

#define SCALE_QK 0.044194173824159216f
#define INV_SQRT2F 0.7071067811865476f

__device__ __forceinline__ void gld_lds16(const bf16* g, bf16* l) {
    __builtin_amdgcn_global_load_lds(
        (const __attribute__((address_space(1))) void*)g,
        (__attribute__((address_space(3))) void*)l, 16, 0, 0);
}

// ---------------------------------------------------------------------------
// Dtype detector: reads first 4096 raw 32-bit words of q. If data is bf16,
// the LOW half of each word is a bf16 of N(0,1): exponent field in ~[110,129].
// If data is f32, the low half is random mantissa bits: ~16% land in range.
// flag = 1  ->  inputs are float32;  flag = 0  ->  inputs are bf16.
// ---------------------------------------------------------------------------
__global__ __launch_bounds__(256) void detect_k(
    const unsigned* __restrict__ q, int* __restrict__ flag)
{
    __shared__ int cnt;
    if (threadIdx.x == 0) cnt = 0;
    __syncthreads();
    int c = 0;
    for (int i = threadIdx.x; i < 4096; i += 256) {
        unsigned e = (q[i] >> 7) & 0xFFu;
        c += (e >= 100u && e <= 140u) ? 1 : 0;
    }
    atomicAdd(&cnt, c);
    __syncthreads();
    if (threadIdx.x == 0) *flag = (cnt < 3000) ? 1 : 0;
}

// Zero the softmax-denominator buffer (16384 floats). 1 block.
__global__ __launch_bounds__(256) void zero_k(float* __restrict__ l)
{
    for (int i = threadIdx.x; i < 16384; i += 256) l[i] = 0.f;
}

// Convert 4 weight matrices [512x512] to internal bf16. grid (128, 4).
__global__ __launch_bounds__(256) void convw_k(
    const void* w0, const void* w1, const void* w2, const void* w3,
    bf16* __restrict__ dst, const int* __restrict__ flag)
{
    const void* srcs[4] = {w0, w1, w2, w3};
    const void* s = srcs[blockIdx.y];
    bf16* d = dst + (size_t)blockIdx.y * 262144;
    const int i = (blockIdx.x * 256 + threadIdx.x) * 8;
    bf16x8 v;
    if (*flag) {
        const float* f = (const float*)s;
        #pragma unroll
        for (int r = 0; r < 8; ++r) v[r] = (bf16)f[i + r];
    } else {
        v = *(const bf16x8*)((const bf16*)s + i);
    }
    *(bf16x8*)(d + i) = v;
}

// Convert 6 length-512 vectors (gamma,beta,bq,bk,bv,bo) to f32. 1 block.
__global__ __launch_bounds__(256) void convp_k(
    const void* p0, const void* p1, const void* p2,
    const void* p3, const void* p4, const void* p5,
    float* __restrict__ dst, const int* __restrict__ flag)
{
    const void* srcs[6] = {p0, p1, p2, p3, p4, p5};
    const int f = *flag;
    for (int i = threadIdx.x; i < 3072; i += 256) {
        const void* s = srcs[i >> 9];
        const int off = i & 511;
        dst[i] = f ? ((const float*)s)[off] : (float)((const bf16*)s)[off];
    }
}

// ---------------------------------------------------------------------------
// GroupNorm: q [4][512][4096] (f32 or bf16 per flag) -> XN [4][4096][512] bf16.
// One block per (batch, group): 16 channels x 4096 pixels.
// ---------------------------------------------------------------------------
__global__ __launch_bounds__(256) void groupnorm_k(
    const void* __restrict__ qraw, const float* __restrict__ gamma,
    const float* __restrict__ beta, bf16* __restrict__ XN,
    const int* __restrict__ flag)
{
    const int tid = threadIdx.x;
    const int b = blockIdx.x >> 5, g = blockIdx.x & 31;
    const int f32 = *flag;
    const size_t base = ((size_t)b * 512 + (size_t)g * 16) * 4096;

    float sum = 0.f, sq = 0.f;
    if (f32) {
        const floatx4* v4 = (const floatx4*)((const float*)qraw + base);
        for (int idx = tid; idx < 16384; idx += 256) {
            floatx4 v = v4[idx];
            #pragma unroll
            for (int r = 0; r < 4; ++r) { float f = v[r]; sum += f; sq += f * f; }
        }
    } else {
        const bf16x8* v8 = (const bf16x8*)((const bf16*)qraw + base);
        for (int idx = tid; idx < 8192; idx += 256) {
            bf16x8 v = v8[idx];
            #pragma unroll
            for (int r = 0; r < 8; ++r) { float f = (float)v[r]; sum += f; sq += f * f; }
        }
    }
    #pragma unroll
    for (int off = 32; off; off >>= 1) {
        sum += __shfl_down(sum, off);
        sq  += __shfl_down(sq, off);
    }
    __shared__ float sS[4], sQ[4];
    __shared__ float s_mean, s_rstd;
    const int wave = tid >> 6, lane = tid & 63;
    if (lane == 0) { sS[wave] = sum; sQ[wave] = sq; }
    __syncthreads();
    if (tid == 0) {
        float ts = sS[0] + sS[1] + sS[2] + sS[3];
        float tq = sQ[0] + sQ[1] + sQ[2] + sQ[3];
        float mean = ts * (1.0f / 65536.0f);
        float var  = tq * (1.0f / 65536.0f) - mean * mean;
        s_mean = mean;
        s_rstd = rsqrtf(fmaxf(var, 0.f) + 1e-6f);
    }
    __syncthreads();
    const float mean = s_mean, rstd = s_rstd;

    const int ci = tid & 15, p0 = tid >> 4;
    const float ga = gamma[g * 16 + ci], be = beta[g * 16 + ci];
    const float* sf = (const float*)qraw + base + (size_t)ci * 4096;
    const bf16*  sb = (const bf16*)qraw  + base + (size_t)ci * 4096;
    bf16* dst = XN + (size_t)b * 4096 * 512 + (size_t)g * 16 + ci;
    for (int p = p0; p < 4096; p += 16) {
        float v = f32 ? sf[p] : (float)sb[p];
        dst[(size_t)p * 512] = (bf16)((v - mean) * rstd * ga + be);
    }
}

// ---------------------------------------------------------------------------
// Generic C = X · Y^T GEMM (operands row-major [rows][K], k-contiguous, bf16).
// 128x128 tile, BK=32, 256 threads (4 waves 2x2, each wave 64x64 via 4x4
// mfma_f32_16x16x32_bf16 frags). global_load_lds width-16 staging (m97).
// Epilogues:
//   0: C = acc + bias[n]                      (Q/K projection, C=[p][o])
//   1: C = acc + bias[m]                      (V projection,   C=[o][p])
//   2: C = exp(min(acc*SCALE, 30)); atomicAdd row-sums into lbuf[m]  (scores)
//   3: C = acc / max(lbuf[m], tiny)           (PV, C=[j][c])
//   4: C = (acc + bias[m] + res[m*N+n]) * INV_SQRT2  (out proj + residual;
//      res/C dtype per flag: 1=f32, 0=bf16)
// ---------------------------------------------------------------------------
template <int EPI>
__global__ __launch_bounds__(256) void gemm_xyt(
    const bf16* __restrict__ X, const bf16* __restrict__ Y,
    void* __restrict__ Cv, int M, int N, int K,
    long sX, long sY, long sC,
    const float* __restrict__ bias,
    float* __restrict__ lbuf, long sL,
    const void* __restrict__ res, long sR,
    const int* __restrict__ flag)
{
    __shared__ __align__(16) bf16 lA[128 * 32];   // 8 KB, [row][32]
    __shared__ __align__(16) bf16 lB[128 * 32];   // 8 KB

    const int tid  = threadIdx.x;
    const int wave = tid >> 6;
    const int lane = tid & 63;
    const int z = blockIdx.z;
    X += (long)z * sX;
    Y += (long)z * sY;
    bf16*  Cb = (bf16*)Cv  + (long)z * sC;
    float* Cf = (float*)Cv + (long)z * sC;
    const int f32 = (EPI == 4) ? *flag : 0;
    const float* resf = (const float*)res;
    const bf16*  resb = (const bf16*)res;
    const size_t zR = (size_t)((long)z * sR);

    const int m0 = blockIdx.y * 128, n0 = blockIdx.x * 128;
    const int wm = (wave >> 1) * 64, wn = (wave & 1) * 64;
    const int fr = lane & 15, quad = lane >> 4;

    const int krow = lane >> 2;          // 0..15 row within a 16-row chunk
    const int kcol = (lane & 3) * 8;     // bf16 column (8 elems = 16 B)

    floatx4 acc[4][4] = {};

    for (int k0 = 0; k0 < K; k0 += 32) {
        // DMA-stage 128x32 A and B tiles. Each wave fills two 16-row chunks
        // of each tile; LDS dest = wave-uniform base + lane*16B, which lands
        // lane's 16B at [krow][kcol] of the chunk (row-major [row][32]).
        #pragma unroll
        for (int ch = 0; ch < 2; ++ch) {
            const int chunk = wave * 2 + ch;           // 0..7
            const int row = chunk * 16 + krow;
            gld_lds16(X + (size_t)(m0 + row) * K + k0 + kcol, &lA[chunk * 512]);
            gld_lds16(Y + (size_t)(n0 + row) * K + k0 + kcol, &lB[chunk * 512]);
        }
        __syncthreads();

        bf16x8 af[4], bf_[4];
        #pragma unroll
        for (int i = 0; i < 4; ++i) {
            af[i]  = *(const bf16x8*)&lA[(wm + i * 16 + fr) * 32 + quad * 8];
            bf_[i] = *(const bf16x8*)&lB[(wn + i * 16 + fr) * 32 + quad * 8];
        }
        #pragma unroll
        for (int i = 0; i < 4; ++i)
            #pragma unroll
            for (int j = 0; j < 4; ++j)
                acc[i][j] = __builtin_amdgcn_mfma_f32_16x16x32_bf16(
                    af[i], bf_[j], acc[i][j], 0, 0, 0);
        __syncthreads();
    }

    // Epilogue. Lane holds D[row = quad*4 + r][col = fr] per 16x16 frag.
    #pragma unroll
    for (int i = 0; i < 4; ++i) {
        const int mg = m0 + wm + i * 16 + quad * 4;   // + r
        if (EPI == 2) {
            float rs[4] = {0.f, 0.f, 0.f, 0.f};
            #pragma unroll
            for (int j = 0; j < 4; ++j) {
                const int ng = n0 + wn + j * 16 + fr;
                #pragma unroll
                for (int r = 0; r < 4; ++r) {
                    float e = __expf(fminf(acc[i][j][r] * SCALE_QK, 30.f));
                    Cb[(size_t)(mg + r) * N + ng] = (bf16)e;
                    rs[r] += e;
                }
            }
            #pragma unroll
            for (int r = 0; r < 4; ++r) {
                float v = rs[r];
                v += __shfl_xor(v, 1);
                v += __shfl_xor(v, 2);
                v += __shfl_xor(v, 4);
                v += __shfl_xor(v, 8);
                if (fr == 0) atomicAdd(&lbuf[z * sL + mg + r], v);
            }
        } else {
            float bm[4], rl[4];
            if (EPI == 1 || EPI == 4) {
                #pragma unroll
                for (int r = 0; r < 4; ++r) bm[r] = bias[mg + r];
            }
            if (EPI == 3) {
                #pragma unroll
                for (int r = 0; r < 4; ++r)
                    rl[r] = 1.0f / fmaxf(lbuf[z * sL + mg + r], 1e-30f);
            }
            #pragma unroll
            for (int j = 0; j < 4; ++j) {
                const int ng = n0 + wn + j * 16 + fr;
                float bn = 0.f;
                if (EPI == 0) bn = bias[ng];
                #pragma unroll
                for (int r = 0; r < 4; ++r) {
                    const size_t o = (size_t)(mg + r) * N + ng;
                    float v = acc[i][j][r];
                    if (EPI == 0) v += bn;
                    if (EPI == 1) v += bm[r];
                    if (EPI == 3) v *= rl[r];
                    if (EPI == 4) {
                        float rv = f32 ? resf[zR + o] : (float)resb[zR + o];
                        v = (v + bm[r] + rv) * INV_SQRT2F;
                        if (f32) { Cf[o] = v; } else { Cb[o] = (bf16)v; }
                    } else {
                        Cb[o] = (bf16)v;
                    }
                }
            }
        }
    }
}

// ---------------------------------------------------------------------------
extern "C" void kernel_launch(void* const* d_in, const int* in_sizes, int n_in,
                              void* d_out, int out_size, void* d_ws, size_t ws_size,
                              hipStream_t stream)
{
    const void* q     = d_in[0];
    const void* gamma = d_in[1];
    const void* beta  = d_in[2];
    const void* wq    = d_in[3];
    const void* bq    = d_in[4];
    const void* wk    = d_in[5];
    const void* bk    = d_in[6];
    const void* wv    = d_in[7];
    const void* bv    = d_in[8];
    const void* wo    = d_in[9];
    const void* bo    = d_in[10];

    const size_t TEN = (size_t)4 * 512 * 4096;      // elems per activation tensor

    char* w = (char*)d_ws;
    int*   flag = (int*)w;   w += 16;
    float* Pf   = (float*)w; w += 6 * 512 * 4;      // gamma,beta,bq,bk,bv,bo (f32)
    bf16*  Wc   = (bf16*)w;  w += 4 * 262144 * 2;   // wq,wk,wv,wo (bf16)
    bf16*  XN   = (bf16*)w;  w += TEN * 2;          // reused as AOt later
    bf16*  Qt   = (bf16*)w;  w += TEN * 2;
    bf16*  V    = (bf16*)w;  w += TEN * 2;
    float* lbuf = (float*)w; w += (size_t)4 * 4096 * 4;
    bf16*  P    = (bf16*)w;
    const size_t base_need = (size_t)(w - (char*)d_ws);
    const bool full = ws_size >= base_need + (size_t)4 * 4096 * 4096 * 2;

    bf16* Kt  = (bf16*)d_out;   // d_out as scratch; fully overwritten at the end
    bf16* AOt = XN;             // XN dead once V is built

    const long sBat = (long)4096 * 512;

    detect_k<<<dim3(1), 256, 0, stream>>>((const unsigned*)q, flag);
    zero_k<<<dim3(1), 256, 0, stream>>>(lbuf);
    convw_k<<<dim3(128, 4), 256, 0, stream>>>(wq, wk, wv, wo, Wc, flag);
    convp_k<<<dim3(1), 256, 0, stream>>>(gamma, beta, bq, bk, bv, bo, Pf, flag);

    groupnorm_k<<<dim3(128), 256, 0, stream>>>(q, Pf, Pf + 512, XN, flag);

    // Qt[p][o] = XN . Wq^T + bq ; Kt likewise.  M=4096(p), N=512(o), K=512
    gemm_xyt<0><<<dim3(4, 32, 4), 256, 0, stream>>>(XN, Wc + 0 * 262144, Qt,
        4096, 512, 512, sBat, 0, sBat, Pf + 1024, nullptr, 0, nullptr, 0, flag);
    gemm_xyt<0><<<dim3(4, 32, 4), 256, 0, stream>>>(XN, Wc + 1 * 262144, Kt,
        4096, 512, 512, sBat, 0, sBat, Pf + 1536, nullptr, 0, nullptr, 0, flag);
    // V[o][p] = Wv . XN^T + bv.  M=512(o), N=4096(p), K=512
    gemm_xyt<1><<<dim3(32, 4, 4), 256, 0, stream>>>(Wc + 2 * 262144, XN, V,
        512, 4096, 512, 0, sBat, sBat, Pf + 2048, nullptr, 0, nullptr, 0, flag);

    if (full) {
        const long sP = (long)4096 * 4096;
        // P[j][i] = exp(scale * <Qt[j], Kt[i]>); lbuf[b][j] += row sums
        gemm_xyt<2><<<dim3(32, 32, 4), 256, 0, stream>>>(Qt, Kt, P,
            4096, 4096, 512, sBat, sBat, sP, nullptr, lbuf, 4096, nullptr, 0, flag);
        // AOt[j][c] = (P . V^T)[j][c] / l[j].  M=4096(j), N=512(c), K=4096
        gemm_xyt<3><<<dim3(4, 32, 4), 256, 0, stream>>>(P, V, AOt,
            4096, 512, 4096, sP, sBat, sBat, nullptr, lbuf, 4096, nullptr, 0, flag);
    } else {
        for (int b = 0; b < 4; ++b) {
            gemm_xyt<2><<<dim3(32, 32, 1), 256, 0, stream>>>(
                Qt + (size_t)b * sBat, Kt + (size_t)b * sBat, P,
                4096, 4096, 512, 0, 0, 0, nullptr, lbuf + (size_t)b * 4096, 0,
                nullptr, 0, flag);
            gemm_xyt<3><<<dim3(4, 32, 1), 256, 0, stream>>>(
                P, V + (size_t)b * sBat, AOt + (size_t)b * sBat,
                4096, 512, 4096, 0, 0, 0, nullptr, lbuf + (size_t)b * 4096, 0,
                nullptr, 0, flag);
        }
    }

    // out[o][p] = (Wo . AOt^T + bo + q) * inv_sqrt2.  M=512(o), N=4096(p), K=512
    gemm_xyt<4><<<dim3(32, 4, 4), 256, 0, stream>>>(Wc + 3 * 262144, AOt, d_out,
        512, 4096, 512, 0, sBat, sBat, Pf + 2560, nullptr, 0, q, sBat, flag);
}

// Round 5
// 551.811 us; speedup vs baseline: 1.1653x; 1.1653x over previous
//
#include <hip/hip_runtime.h>

typedef __bf16 bf16;
typedef __bf16 bf16x8 __attribute__((ext_vector_type(8)));
typedef float floatx4 __attribute__((ext_vector_type(4)));

#define SCALE_QK 0.044194173824159216f
#define INV_SQRT2F 0.7071067811865476f
#define TEN  8388608L     // elems per activation tensor (4*512*4096)
#define SBAT 2097152L     // elems per batch (4096*512)
#define SPB  16777216L    // P elems per batch (4096*4096)

// ---------------------------------------------------------------------------
// Dtype detector (verified R3: inputs are f32 -> flag=1; bf16 -> flag=0).
// ---------------------------------------------------------------------------
__global__ __launch_bounds__(256) void detect_k(
    const unsigned* __restrict__ q, int* __restrict__ flag)
{
    __shared__ int cnt;
    if (threadIdx.x == 0) cnt = 0;
    __syncthreads();
    int c = 0;
    for (int i = threadIdx.x; i < 4096; i += 256) {
        unsigned e = (q[i] >> 7) & 0xFFu;
        c += (e >= 100u && e <= 140u) ? 1 : 0;
    }
    atomicAdd(&cnt, c);
    __syncthreads();
    if (threadIdx.x == 0) *flag = (cnt < 3000) ? 1 : 0;
}

__global__ __launch_bounds__(256) void zero_k(float* __restrict__ l)
{
    for (int i = threadIdx.x; i < 16384; i += 256) l[i] = 0.f;
}

__global__ __launch_bounds__(256) void convw_k(
    const void* w0, const void* w1, const void* w2, const void* w3,
    bf16* __restrict__ dst, const int* __restrict__ flag)
{
    const void* srcs[4] = {w0, w1, w2, w3};
    const void* s = srcs[blockIdx.y];
    bf16* d = dst + (size_t)blockIdx.y * 262144;
    const int i = (blockIdx.x * 256 + threadIdx.x) * 8;
    bf16x8 v;
    if (*flag) {
        const float* f = (const float*)s;
        #pragma unroll
        for (int r = 0; r < 8; ++r) v[r] = (bf16)f[i + r];
    } else {
        v = *(const bf16x8*)((const bf16*)s + i);
    }
    *(bf16x8*)(d + i) = v;
}

__global__ __launch_bounds__(256) void convp_k(
    const void* p0, const void* p1, const void* p2,
    const void* p3, const void* p4, const void* p5,
    float* __restrict__ dst, const int* __restrict__ flag)
{
    const void* srcs[6] = {p0, p1, p2, p3, p4, p5};
    const int f = *flag;
    for (int i = threadIdx.x; i < 3072; i += 256) {
        const void* s = srcs[i >> 9];
        const int off = i & 511;
        dst[i] = f ? ((const float*)s)[off] : (float)((const bf16*)s)[off];
    }
}

// ---------------------------------------------------------------------------
// GroupNorm: q [4][512][4096] -> XN [4][4096][512] bf16.
// Block per (batch,group). Pass 2: per-thread register transpose —
// 16 coalesced row reads -> one 32 B contiguous write per pixel.
// ---------------------------------------------------------------------------
__global__ __launch_bounds__(256) void groupnorm_k(
    const void* __restrict__ qraw, const float* __restrict__ gamma,
    const float* __restrict__ beta, bf16* __restrict__ XN,
    const int* __restrict__ flag)
{
    const int tid = threadIdx.x;
    const int b = blockIdx.x >> 5, g = blockIdx.x & 31;
    const int f32 = *flag;
    const size_t base = ((size_t)b * 512 + (size_t)g * 16) * 4096;
    const float* sf = (const float*)qraw + base;
    const bf16*  sb = (const bf16*)qraw + base;

    float sum = 0.f, sq = 0.f;
    if (f32) {
        const floatx4* v4 = (const floatx4*)sf;
        for (int idx = tid; idx < 16384; idx += 256) {
            floatx4 v = v4[idx];
            #pragma unroll
            for (int r = 0; r < 4; ++r) { float f = v[r]; sum += f; sq += f * f; }
        }
    } else {
        const bf16x8* v8 = (const bf16x8*)sb;
        for (int idx = tid; idx < 8192; idx += 256) {
            bf16x8 v = v8[idx];
            #pragma unroll
            for (int r = 0; r < 8; ++r) { float f = (float)v[r]; sum += f; sq += f * f; }
        }
    }
    #pragma unroll
    for (int off = 32; off; off >>= 1) {
        sum += __shfl_down(sum, off);
        sq  += __shfl_down(sq, off);
    }
    __shared__ float sS[4], sQ[4];
    __shared__ float s_mean, s_rstd;
    const int wave = tid >> 6, lane = tid & 63;
    if (lane == 0) { sS[wave] = sum; sQ[wave] = sq; }
    __syncthreads();
    if (tid == 0) {
        float ts = sS[0] + sS[1] + sS[2] + sS[3];
        float tq = sQ[0] + sQ[1] + sQ[2] + sQ[3];
        float mean = ts * (1.0f / 65536.0f);
        float var  = tq * (1.0f / 65536.0f) - mean * mean;
        s_mean = mean;
        s_rstd = rsqrtf(fmaxf(var, 0.f) + 1e-6f);
    }
    __syncthreads();
    const float mean = s_mean, rstd = s_rstd;

    float ga[16], be[16];
    #pragma unroll
    for (int c = 0; c < 16; ++c) {
        ga[c] = gamma[g * 16 + c] * rstd;
        be[c] = beta[g * 16 + c] - mean * ga[c];
    }
    bf16* dst = XN + (size_t)b * SBAT + (size_t)g * 16;
    for (int p0 = 0; p0 < 4096; p0 += 256) {
        const int p = p0 + tid;
        bf16x8 o0, o1;
        #pragma unroll
        for (int c = 0; c < 8; ++c) {
            float v = f32 ? sf[(size_t)c * 4096 + p] : (float)sb[(size_t)c * 4096 + p];
            o0[c] = (bf16)(v * ga[c] + be[c]);
        }
        #pragma unroll
        for (int c = 0; c < 8; ++c) {
            float v = f32 ? sf[(size_t)(c + 8) * 4096 + p] : (float)sb[(size_t)(c + 8) * 4096 + p];
            o1[c] = (bf16)(v * ga[c + 8] + be[c + 8]);
        }
        bf16* dp = dst + (size_t)p * 512;
        *(bf16x8*)dp = o0;
        *(bf16x8*)(dp + 8) = o1;
    }
}

// ---------------------------------------------------------------------------
// Reduce split-K partials: AOt = (P0 + P1) / l.  Part: [2][4][4096][512] bf16.
// ---------------------------------------------------------------------------
__global__ __launch_bounds__(256) void reduce_k(
    const bf16* __restrict__ Part, const float* __restrict__ lbuf,
    bf16* __restrict__ AOt)
{
    const size_t i8 = ((size_t)blockIdx.x * 256 + threadIdx.x) * 8;
    const int b = (int)(i8 >> 21);
    const int j = (int)((i8 >> 9) & 4095);
    const float rl = 1.0f / fmaxf(lbuf[b * 4096 + j], 1e-30f);
    bf16x8 a = *(const bf16x8*)&Part[i8];
    bf16x8 c = *(const bf16x8*)&Part[TEN + i8];
    bf16x8 o;
    #pragma unroll
    for (int r = 0; r < 8; ++r) o[r] = (bf16)(((float)a[r] + (float)c[r]) * rl);
    *(bf16x8*)&AOt[i8] = o;
}

// ---------------------------------------------------------------------------
// C = X · Y^T GEMM, k-contiguous operands, 128x128x32 tiles, 4 waves (2x2),
// 16x16x32 bf16 MFMA. Explicit reg-prefetch + double-buffered LDS: one
// barrier per K-iter, global loads for iter k+2 in flight during MFMA(k).
// Epilogues (all bf16 outs staged through LDS for coalesced 16B stores):
//   0: C = acc + bias[n]                          (Q/K proj, C=[p][o])
//   1: C = acc + bias[m]                          (V proj,   C=[o][p])
//   2: C = exp(min(acc*SCALE,30)); atomic rowsum  (scores -> P)
//   3: C = acc / l[m]                             (PV, fallback path)
//   4: C = (acc + bias[m] + res) * INV_SQRT2      (out proj + residual)
//   5: C = acc  (PV split-K partial; z = batch*2 + split, hardcoded map)
// ---------------------------------------------------------------------------
template <int EPI>
__global__ __launch_bounds__(256, 3) void gemm_xyt(
    const bf16* __restrict__ Xb, const bf16* __restrict__ Yb,
    void* __restrict__ Cv, int N, int K, int lda, int ldb,
    long sX, long sY, long sC,
    const float* __restrict__ bias,
    float* __restrict__ lbuf, long sL,
    const void* __restrict__ res, long sR,
    const int* __restrict__ flag)
{
    __shared__ __align__(16) bf16 smem[17408];   // 32KB dbuf, 34KB epilogue

    const int tid  = threadIdx.x;
    const int wave = tid >> 6;
    const int lane = tid & 63;
    const int z = blockIdx.z;

    const bf16* X; const bf16* Y; bf16* Cb; float* Cf = nullptr;
    int zb = z;
    if (EPI == 5) {
        const int b = z >> 1, s = z & 1;
        X  = Xb + (size_t)b * SPB  + (size_t)s * 2048;
        Y  = Yb + (size_t)b * SBAT + (size_t)s * 2048;
        Cb = (bf16*)Cv + (size_t)s * TEN + (size_t)b * SBAT;
        zb = b;
    } else {
        X  = Xb + (long)z * sX;
        Y  = Yb + (long)z * sY;
        Cb = (bf16*)Cv  + (long)z * sC;
        Cf = (float*)Cv + (long)z * sC;
    }
    const int f32o = (EPI == 4) ? *flag : 0;

    const int m0 = blockIdx.y * 128, n0 = blockIdx.x * 128;
    const int wm = (wave >> 1) * 64, wn = (wave & 1) * 64;
    const int fr = lane & 15, quad = lane >> 4;

    // staging: thread covers rows {srow, srow+64} x 8 cols of A and B tiles
    const int srow = tid >> 2;
    const int scol = (tid & 3) * 8;
    const bf16* pX = X + (size_t)(m0 + srow) * lda + scol;
    const bf16* pY = Y + (size_t)(n0 + srow) * ldb + scol;
    const size_t oX = (size_t)64 * lda, oY = (size_t)64 * ldb;
    const int ldsOff = srow * 32 + scol;

    bf16x8 rA0, rA1, rB0, rB1;
    const int NK = K >> 5;

    auto loadT = [&](int k) {
        const bf16* x = pX + k * 32;
        const bf16* y = pY + k * 32;
        rA0 = *(const bf16x8*)x;
        rA1 = *(const bf16x8*)(x + oX);
        rB0 = *(const bf16x8*)y;
        rB1 = *(const bf16x8*)(y + oY);
    };
    auto writeT = [&](int p) {
        bf16* dA = smem + p * 8192;
        *(bf16x8*)&dA[ldsOff]           = rA0;
        *(bf16x8*)&dA[2048 + ldsOff]    = rA1;
        *(bf16x8*)&dA[4096 + ldsOff]    = rB0;
        *(bf16x8*)&dA[6144 + ldsOff]    = rB1;
    };

    floatx4 acc[4][4] = {};

    loadT(0);
    writeT(0);
    if (NK > 1) loadT(1);
    __syncthreads();

    for (int k = 0; k < NK; ++k) {
        const int p = k & 1;
        const bf16* bA = smem + p * 8192;
        const bf16* bB = bA + 4096;
        bf16x8 af[4], bfr[4];
        #pragma unroll
        for (int i = 0; i < 4; ++i) {
            af[i]  = *(const bf16x8*)&bA[(wm + i * 16 + fr) * 32 + quad * 8];
            bfr[i] = *(const bf16x8*)&bB[(wn + i * 16 + fr) * 32 + quad * 8];
        }
        if (k + 1 < NK) writeT(1 - p);      // regs(k+1) -> other LDS buffer
        if (k + 2 < NK) loadT(k + 2);       // prefetch k+2 into regs
        #pragma unroll
        for (int i = 0; i < 4; ++i)
            #pragma unroll
            for (int j = 0; j < 4; ++j)
                acc[i][j] = __builtin_amdgcn_mfma_f32_16x16x32_bf16(
                    af[i], bfr[j], acc[i][j], 0, 0, 0);
        __syncthreads();
    }

    // ---- finalize values in-place (lane holds D[quad*4+r][fr] per frag) ----
    #pragma unroll
    for (int i = 0; i < 4; ++i) {
        const int mg = m0 + wm + i * 16 + quad * 4;
        float bmr[4], rl[4];
        if (EPI == 1 || EPI == 4) {
            #pragma unroll
            for (int r = 0; r < 4; ++r) bmr[r] = bias[mg + r];
        }
        if (EPI == 3) {
            #pragma unroll
            for (int r = 0; r < 4; ++r)
                rl[r] = 1.0f / fmaxf(lbuf[zb * sL + mg + r], 1e-30f);
        }
        if (EPI == 2) {
            float rs[4] = {0.f, 0.f, 0.f, 0.f};
            #pragma unroll
            for (int j = 0; j < 4; ++j)
                #pragma unroll
                for (int r = 0; r < 4; ++r) {
                    float e = __expf(fminf(acc[i][j][r] * SCALE_QK, 30.f));
                    acc[i][j][r] = e;
                    rs[r] += e;
                }
            #pragma unroll
            for (int r = 0; r < 4; ++r) {
                float v = rs[r];
                v += __shfl_xor(v, 1);
                v += __shfl_xor(v, 2);
                v += __shfl_xor(v, 4);
                v += __shfl_xor(v, 8);
                if (fr == 0) atomicAdd(&lbuf[zb * sL + mg + r], v);
            }
        } else if (EPI != 5) {
            #pragma unroll
            for (int j = 0; j < 4; ++j) {
                const int ng = n0 + wn + j * 16 + fr;
                #pragma unroll
                for (int r = 0; r < 4; ++r) {
                    float v = acc[i][j][r];
                    if (EPI == 0) v += bias[ng];
                    if (EPI == 1) v += bmr[r];
                    if (EPI == 3) v *= rl[r];
                    if (EPI == 4) v += bmr[r];   // residual+scale at readout
                    acc[i][j][r] = v;
                }
            }
        }
    }

    // ---- staged, coalesced stores ----
    if (EPI != 4) {
        bf16* ct = smem;                       // [128][132] bf16
        #pragma unroll
        for (int i = 0; i < 4; ++i)
            #pragma unroll
            for (int j = 0; j < 4; ++j)
                #pragma unroll
                for (int r = 0; r < 4; ++r)
                    ct[(wm + i * 16 + quad * 4 + r) * 132 + wn + j * 16 + fr] =
                        (bf16)acc[i][j][r];
        __syncthreads();
        #pragma unroll
        for (int w = 0; w < 8; ++w) {
            const int idx = w * 2048 + tid * 8;
            const int row = idx >> 7, col = idx & 127;
            bf16x8 v = *(const bf16x8*)&ct[row * 132 + col];
            *(bf16x8*)&Cb[(size_t)(m0 + row) * N + n0 + col] = v;
        }
    } else if (f32o) {
        float* ct = (float*)smem;              // [64][132] f32, two halves
        const float* rres = (const float*)res + (size_t)z * sR;
        #pragma unroll
        for (int h = 0; h < 2; ++h) {
            if ((wave >> 1) == h) {
                #pragma unroll
                for (int i = 0; i < 4; ++i)
                    #pragma unroll
                    for (int j = 0; j < 4; ++j)
                        #pragma unroll
                        for (int r = 0; r < 4; ++r)
                            ct[(i * 16 + quad * 4 + r) * 132 + wn + j * 16 + fr] =
                                acc[i][j][r];
            }
            __syncthreads();
            #pragma unroll
            for (int w = 0; w < 8; ++w) {
                const int idx = (w * 256 + tid) * 4;
                const int row = idx >> 7, col = idx & 127;
                const size_t o = (size_t)(m0 + h * 64 + row) * N + n0 + col;
                floatx4 v = *(const floatx4*)&ct[row * 132 + col];
                floatx4 rv = *(const floatx4*)&rres[o];
                #pragma unroll
                for (int e = 0; e < 4; ++e) v[e] = (v[e] + rv[e]) * INV_SQRT2F;
                *(floatx4*)&Cf[o] = v;
            }
            __syncthreads();
        }
    } else {
        // bf16-residual fallback (correctness path; not hit with f32 inputs)
        const bf16* resb = (const bf16*)res + (size_t)z * sR;
        #pragma unroll
        for (int i = 0; i < 4; ++i) {
            const int mg = m0 + wm + i * 16 + quad * 4;
            #pragma unroll
            for (int j = 0; j < 4; ++j) {
                const int ng = n0 + wn + j * 16 + fr;
                #pragma unroll
                for (int r = 0; r < 4; ++r) {
                    const size_t o = (size_t)(mg + r) * N + ng;
                    Cb[o] = (bf16)((acc[i][j][r] + (float)resb[o]) * INV_SQRT2F);
                }
            }
        }
    }
}

// ---------------------------------------------------------------------------
extern "C" void kernel_launch(void* const* d_in, const int* in_sizes, int n_in,
                              void* d_out, int out_size, void* d_ws, size_t ws_size,
                              hipStream_t stream)
{
    const void* q     = d_in[0];
    const void* gamma = d_in[1];
    const void* beta  = d_in[2];
    const void* wq    = d_in[3];
    const void* bq    = d_in[4];
    const void* wk    = d_in[5];
    const void* bk    = d_in[6];
    const void* wv    = d_in[7];
    const void* bv    = d_in[8];
    const void* wo    = d_in[9];
    const void* bo    = d_in[10];

    char* w = (char*)d_ws;
    int*   flag = (int*)w;   w += 16;
    float* Pf   = (float*)w; w += 6 * 512 * 4;      // gamma,beta,bq,bk,bv,bo
    bf16*  Wc   = (bf16*)w;  w += 4 * 262144 * 2;   // wq,wk,wv,wo bf16
    bf16*  XN   = (bf16*)w;  w += TEN * 2;          // reused as AOt
    bf16*  Qt   = (bf16*)w;  w += TEN * 2;
    bf16*  V    = (bf16*)w;  w += TEN * 2;
    float* lbuf = (float*)w; w += (size_t)4 * 4096 * 4;
    bf16*  P    = (bf16*)w;
    const size_t base_need = (size_t)(w - (char*)d_ws);
    const bool full = ws_size >= base_need + (size_t)4 * 4096 * 4096 * 2;

    bf16* Kt   = (bf16*)d_out;   // scratch: dead before PV partials land
    bf16* Part = (bf16*)d_out;   // split-K partials [2][4][4096][512]
    bf16* AOt  = XN;

    detect_k<<<dim3(1), 256, 0, stream>>>((const unsigned*)q, flag);
    zero_k<<<dim3(1), 256, 0, stream>>>(lbuf);
    convw_k<<<dim3(128, 4), 256, 0, stream>>>(wq, wk, wv, wo, Wc, flag);
    convp_k<<<dim3(1), 256, 0, stream>>>(gamma, beta, bq, bk, bv, bo, Pf, flag);

    groupnorm_k<<<dim3(128), 256, 0, stream>>>(q, Pf, Pf + 512, XN, flag);

    // Qt[p][o] = XN . Wq^T + bq ; Kt likewise.  N=512, K=512
    gemm_xyt<0><<<dim3(4, 32, 4), 256, 0, stream>>>(XN, Wc + 0 * 262144, Qt,
        512, 512, 512, 512, SBAT, 0, SBAT, Pf + 1024, nullptr, 0, nullptr, 0, flag);
    gemm_xyt<0><<<dim3(4, 32, 4), 256, 0, stream>>>(XN, Wc + 1 * 262144, Kt,
        512, 512, 512, 512, SBAT, 0, SBAT, Pf + 1536, nullptr, 0, nullptr, 0, flag);
    // V[o][p] = Wv . XN^T + bv.  N=4096, K=512
    gemm_xyt<1><<<dim3(32, 4, 4), 256, 0, stream>>>(Wc + 2 * 262144, XN, V,
        4096, 512, 512, 512, 0, SBAT, SBAT, Pf + 2048, nullptr, 0, nullptr, 0, flag);

    if (full) {
        // P[j][i] = exp(scale*<Qt[j],Kt[i]>); lbuf[b][j] += rowsums
        gemm_xyt<2><<<dim3(32, 32, 4), 256, 0, stream>>>(Qt, Kt, P,
            4096, 512, 512, 512, SBAT, SBAT, SPB, nullptr, lbuf, 4096,
            nullptr, 0, flag);
        // PV split-K x2 partials (z = b*2 + s), K=2048 each
        gemm_xyt<5><<<dim3(4, 32, 8), 256, 0, stream>>>(P, V, Part,
            512, 2048, 4096, 4096, 0, 0, 0, nullptr, nullptr, 0,
            nullptr, 0, flag);
        // AOt = (P0 + P1) / l
        reduce_k<<<dim3(4096), 256, 0, stream>>>(Part, lbuf, AOt);
    } else {
        for (int b = 0; b < 4; ++b) {
            gemm_xyt<2><<<dim3(32, 32, 1), 256, 0, stream>>>(
                Qt + (size_t)b * SBAT, Kt + (size_t)b * SBAT, P,
                4096, 512, 512, 512, 0, 0, 0, nullptr,
                lbuf + (size_t)b * 4096, 0, nullptr, 0, flag);
            gemm_xyt<3><<<dim3(4, 32, 1), 256, 0, stream>>>(
                P, V + (size_t)b * SBAT, AOt + (size_t)b * SBAT,
                512, 4096, 4096, 4096, 0, 0, 0, nullptr,
                lbuf + (size_t)b * 4096, 0, nullptr, 0, flag);
        }
    }

    // out[o][p] = (Wo . AOt^T + bo + q) * inv_sqrt2.  N=4096, K=512
    gemm_xyt<4><<<dim3(32, 4, 4), 256, 0, stream>>>(Wc + 3 * 262144, AOt, d_out,
        4096, 512, 512, 512, 0, SBAT, SBAT, Pf + 2560, nullptr, 0, q, SBAT, flag);
}